// Round 7
// baseline (1035.413 us; speedup 1.0000x reference)
//
#include <hip/hip_runtime.h>
#include <math.h>

typedef _Float16 f16;
typedef _Float16 f16x8 __attribute__((ext_vector_type(8)));
typedef float    f32x4 __attribute__((ext_vector_type(4)));
typedef unsigned int u32;
typedef unsigned long long u64;

#define NHEADS 128
#define KLEN   8192
#define DDIM   128
#define SDIM   256
#define NROWS  (NHEADS * KLEN)       // 1,048,576 k-rows
#define SCALE  1.2533141373155003f   // sqrt(pi/2)
#define TAU    2e-5f                 // suspect threshold (f16x3 sigma ~1e-6; round-3-validated)

// ---- workspace layout ----
// [0, 1MiB)            : qs16 f16 [128 heads][16 q][256 s]
// [1MiB, +64KiB)       : Gh_t f16 [256 s][128 d]  (hi, transposed)
// [+64K, +128K)        : Gl_t f16 [256 s][128 d]  (lo * 4096, transposed)
// [+128K, +256K)       : Gt   f32 [256 s][128 d]  (exact, transposed)
// [2MiB, 2MiB+32MiB)   : packed sign bits, u32[1M rows][8]
// suspect MASK (u32[1M rows][8], 32MB) lives in d_out (dead until est).
#define QS_OFF     0
#define GH_OFF     (1u << 20)
#define GL_OFF     ((1u << 20) + (64u << 10))
#define GT_OFF     ((1u << 20) + (128u << 10))
#define PACKED_OFF (2u << 20)

// ------------------------------------------------------------------
// Sequential f32 dot, d-ascending, single-rounding FMA per step —
// bitwise-matches the numpy reference path (validated round 3).
__device__ __forceinline__ float seq_dot_np(const float* __restrict__ a,
                                            const float* __restrict__ gcol) {
  float acc = 0.0f;
  #pragma unroll 8
  for (int d = 0; d < DDIM; ++d)
    acc = __builtin_fmaf(a[d], gcol[d], acc);
  return acc;
}

// ------------------------------------------------------------------
// prep: q_sketch = q @ G  (f32 accumulate, store f16)
__global__ void prep_qs_kernel(const float* __restrict__ q,
                               const float* __restrict__ G,
                               f16* __restrict__ qs16) {
  int idx = blockIdx.x * 256 + threadIdx.x;      // 524288
  int s  = idx & 255;
  int hq = idx >> 8;
  const float* qr = q + (size_t)hq * DDIM;
  float acc = 0.f;
  #pragma unroll 8
  for (int d = 0; d < DDIM; ++d) acc += qr[d] * G[d * SDIM + s];
  qs16[idx] = (f16)acc;
}

// prep: G -> f16 transposed hi + f16 transposed (lo*4096) + f32 exact copy
__global__ void prep_g_kernel(const float* __restrict__ G,
                              f16* __restrict__ gh, f16* __restrict__ gl,
                              float* __restrict__ gt) {
  int idx = blockIdx.x * 256 + threadIdx.x;      // 32768
  int d = idx & 127;
  int s = idx >> 7;
  float g = G[d * SDIM + s];
  f16 h = (f16)g;
  gh[s * DDIM + d] = h;
  gl[s * DDIM + d] = (f16)((g - (float)h) * 4096.0f);
  gt[s * DDIM + d] = g;
}

// ------------------------------------------------------------------
// Pass A: proj = k @ G via f16x3 MFMA emulation (round-3 arithmetic),
// round-5/6 structure: no LDS, no barriers, no atomics; B-frags from
// L1/L2 (Gh+Gl = 128KB). 16 rows/wave to keep VGPR ~110 -> 4-5 w/SIMD.
// grid: 16384 wgs * 256 thr; wave w owns rows wg*64 + w*16 .. +15.
__launch_bounds__(256)
__global__ void proj_sign_kernel(const float* __restrict__ kmat,
                                 const f16* __restrict__ gh,
                                 const f16* __restrict__ gl,
                                 u32* __restrict__ packed,
                                 u32* __restrict__ smask) {
  const int tid  = threadIdx.x;
  const int lane = tid & 63;
  const int w    = tid >> 6;
  const int base = blockIdx.x * 64 + w * 16;     // global k-row base (linear)
  const int g4 = lane >> 4;
  const int ln = lane & 15;

  // ---- A fragments (hi/lo f16 split) for 16 rows ----
  // A[m][kk]: m = lane&15, kk = 8*(lane>>4)+j
  f16x8 Ah[4], Al[4];
  {
    const float* kr = kmat + (size_t)(base + ln) * DDIM;
    #pragma unroll
    for (int c = 0; c < 4; ++c) {
      const float* p0 = kr + c * 32 + g4 * 8;
      float4 a0 = *(const float4*)p0;
      float4 a1 = *(const float4*)(p0 + 4);
      float af[8] = {a0.x, a0.y, a0.z, a0.w, a1.x, a1.y, a1.z, a1.w};
      f16x8 hh, ll;
      #pragma unroll
      for (int j = 0; j < 8; ++j) {
        f16 h = (f16)af[j];
        hh[j] = h;
        ll[j] = (f16)((af[j] - (float)h) * 4096.0f);
      }
      Ah[c] = hh;
      Al[c] = ll;
    }
  }

  u32 pw[8] = {0};   // packed sign words  (lane<16: row base+lane)
  u32 sw[8] = {0};   // suspect mask words

  #pragma unroll
  for (int tl = 0; tl < 16; ++tl) {              // 16 s-tiles of 16
    const int s = tl * 16 + ln;
    const f16* bhp = gh + (size_t)s * DDIM + g4 * 8;
    const f16* blp = gl + (size_t)s * DDIM + g4 * 8;
    f16x8 Bh[4], Bl[4];
    #pragma unroll
    for (int c = 0; c < 4; ++c) {
      Bh[c] = *(const f16x8*)(bhp + c * 32);
      Bl[c] = *(const f16x8*)(blp + c * 32);
    }
    // round-3 accumulation order: ah chain (4 MFMA), al chain (8 MFMA)
    f32x4 ah = {0,0,0,0}, al = {0,0,0,0};
    #pragma unroll
    for (int c = 0; c < 4; ++c) {
      ah = __builtin_amdgcn_mfma_f32_16x16x32_f16(Ah[c], Bh[c], ah, 0, 0, 0);
      al = __builtin_amdgcn_mfma_f32_16x16x32_f16(Ah[c], Bl[c], al, 0, 0, 0);
      al = __builtin_amdgcn_mfma_f32_16x16x32_f16(Al[c], Bh[c], al, 0, 0, 0);
    }
    float p[4];
    #pragma unroll
    for (int r = 0; r < 4; ++r)
      p[r] = ah[r] + al[r] * 2.44140625e-4f;     // 1/4096

    // ---- sign ballots ----
    {
      u64 b0 = __ballot(p[0] > 0.0f ? 1 : 0);
      u64 b1 = __ballot(p[1] > 0.0f ? 1 : 0);
      u64 b2 = __ballot(p[2] > 0.0f ? 1 : 0);
      u64 b3 = __ballot(p[3] > 0.0f ? 1 : 0);
      if (lane < 16) {
        int r = lane & 3;
        u64 b = (r == 0) ? b0 : (r == 1) ? b1 : (r == 2) ? b2 : b3;
        u32 sh = 16u * (u32)(lane >> 2);
        pw[tl >> 1] |= ((u32)((b >> sh) & 0xffffu)) << (16 * (tl & 1));
      }
    }

    // ---- suspect ballots, guarded (trip prob ~0.6% per tile) ----
    float mn = fminf(fminf(__builtin_fabsf(p[0]), __builtin_fabsf(p[1])),
                     fminf(__builtin_fabsf(p[2]), __builtin_fabsf(p[3])));
    if (__any(mn < TAU ? 1 : 0)) {
      u64 t0 = __ballot(__builtin_fabsf(p[0]) < TAU ? 1 : 0);
      u64 t1 = __ballot(__builtin_fabsf(p[1]) < TAU ? 1 : 0);
      u64 t2 = __ballot(__builtin_fabsf(p[2]) < TAU ? 1 : 0);
      u64 t3 = __ballot(__builtin_fabsf(p[3]) < TAU ? 1 : 0);
      if (lane < 16) {
        int r = lane & 3;
        u64 t = (r == 0) ? t0 : (r == 1) ? t1 : (r == 2) ? t2 : t3;
        u32 sh = 16u * (u32)(lane >> 2);
        sw[tl >> 1] |= ((u32)((t >> sh) & 0xffffu)) << (16 * (tl & 1));
      }
    }
  }

  if (lane < 16) {
    size_t row = (size_t)(base + lane);
    uint4 v0, v1, m0, m1;
    v0.x = pw[0]; v0.y = pw[1]; v0.z = pw[2]; v0.w = pw[3];
    v1.x = pw[4]; v1.y = pw[5]; v1.z = pw[6]; v1.w = pw[7];
    m0.x = sw[0]; m0.y = sw[1]; m0.z = sw[2]; m0.w = sw[3];
    m1.x = sw[4]; m1.y = sw[5]; m1.z = sw[6]; m1.w = sw[7];
    *(uint4*)(packed + row * 8)     = v0;
    *(uint4*)(packed + row * 8 + 4) = v1;
    *(uint4*)(smask  + row * 8)     = m0;
    *(uint4*)(smask  + row * 8 + 4) = m1;
  }
}

// ------------------------------------------------------------------
// Pass B: one thread per k-row; ~6K suspects total -> mask-scan bound.
__global__ void fixup_kernel(const float* __restrict__ kmat,
                             const float* __restrict__ gt,
                             u32* __restrict__ packed,
                             const u32* __restrict__ smask) {
  int row = blockIdx.x * 256 + threadIdx.x;
  if (row >= NROWS) return;
  const u32* mp = smask + (size_t)row * 8;
  uint4 m0 = *(const uint4*)mp;
  uint4 m1 = *(const uint4*)(mp + 4);
  u32 mw[8] = {m0.x, m0.y, m0.z, m0.w, m1.x, m1.y, m1.z, m1.w};
  if (!(mw[0] | mw[1] | mw[2] | mw[3] | mw[4] | mw[5] | mw[6] | mw[7])) return;
  const float* a = kmat + (size_t)row * DDIM;
  #pragma unroll
  for (int wd = 0; wd < 8; ++wd) {
    u32 m = mw[wd];
    if (!m) continue;
    u32 pk = packed[(size_t)row * 8 + wd];
    while (m) {
      int b = __ffs(m) - 1;  m &= m - 1;
      int s = wd * 32 + b;
      float acc = seq_dot_np(a, gt + (size_t)s * DDIM);
      if (acc > 0.0f) pk |= (1u << b);
      else            pk &= ~(1u << b);
    }
    packed[(size_t)row * 8 + wd] = pk;
  }
}

// ------------------------------------------------------------------
// est = q_sketch @ sign^T, bits -> ±1 f16 on the fly, MFMA f16, f32 out
__launch_bounds__(256)
__global__ void est_kernel(const f16* __restrict__ qs16,
                           const u32* __restrict__ packed,
                           float* __restrict__ out) {
  const int tid  = threadIdx.x;
  const int lane = tid & 63;
  const int w    = tid >> 6;
  const int wg   = blockIdx.x;
  const int head   = wg >> 5;
  const int kchunk = (wg & 31) * 256;
  const int g4 = lane >> 4, ln = lane & 15;

  f16x8 aq[8];
  const f16* qb = qs16 + (size_t)head * 16 * SDIM;
  #pragma unroll
  for (int c = 0; c < 8; ++c)
    aq[c] = *(const f16x8*)(qb + ln * SDIM + c * 32 + g4 * 8);

  const int kb = kchunk + w * 64;
  #pragma unroll
  for (int kt = 0; kt < 4; ++kt) {
    int krow = kb + kt * 16 + ln;
    const u32* bp = packed + (size_t)(head * KLEN + krow) * 8;
    uint4 q0 = *(const uint4*)bp;
    uint4 q1 = *(const uint4*)(bp + 4);
    u32 b32[8] = {q0.x, q0.y, q0.z, q0.w, q1.x, q1.y, q1.z, q1.w};
    f32x4 acc = {0, 0, 0, 0};
    #pragma unroll
    for (int c = 0; c < 8; ++c) {
      u32 byte8 = (b32[c] >> (8 * g4)) & 0xffu;
      union { u32 u[4]; f16x8 h; } sv;
      #pragma unroll
      for (int pp = 0; pp < 4; ++pp) {
        u32 v = 0x3C003C00u;
        v |= ((byte8 >> (2 * pp))     & 1u) ? 0u : 0x8000u;
        v |= ((byte8 >> (2 * pp + 1)) & 1u) ? 0u : 0x80000000u;
        sv.u[pp] = v;
      }
      acc = __builtin_amdgcn_mfma_f32_16x16x32_f16(aq[c], sv.h, acc, 0, 0, 0);
    }
    float* ob = out + (size_t)(head * 16) * KLEN + kb + kt * 16 + ln;
    #pragma unroll
    for (int r = 0; r < 4; ++r) {
      int qrow = g4 * 4 + r;
      ob[(size_t)qrow * KLEN] = acc[r] * SCALE;
    }
  }
}

// ------------------------------------------------------------------
extern "C" void kernel_launch(void* const* d_in, const int* in_sizes, int n_in,
                              void* d_out, int out_size, void* d_ws, size_t ws_size,
                              hipStream_t stream) {
  const float* q = (const float*)d_in[0];
  const float* k = (const float*)d_in[1];
  const float* G = (const float*)d_in[2];
  float* out = (float*)d_out;
  char* ws = (char*)d_ws;

  f16*   qs16   = (f16*)(ws + QS_OFF);
  f16*   gh     = (f16*)(ws + GH_OFF);
  f16*   gl     = (f16*)(ws + GL_OFF);
  float* gt     = (float*)(ws + GT_OFF);
  u32*   packed = (u32*)(ws + PACKED_OFF);

  // suspect mask in d_out (32MB << 67MB); fully rewritten by proj_sign
  // each call; est overwrites d_out afterwards (stream-ordered).
  u32* smask = (u32*)d_out;

  prep_qs_kernel<<<2048, 256, 0, stream>>>(q, G, qs16);
  prep_g_kernel<<<128, 256, 0, stream>>>(G, gh, gl, gt);
  proj_sign_kernel<<<16384, 256, 0, stream>>>(k, gh, gl, packed, smask);
  fixup_kernel<<<4096, 256, 0, stream>>>(k, gt, packed, smask);
  est_kernel<<<4096, 256, 0, stream>>>(qs16, packed, out);
}